// Round 4
// baseline (37610.239 us; speedup 1.0000x reference)
//
#include <hip/hip_runtime.h>
#include <math.h>

#define DM   1024
#define BSZ  4
#define LSEQ 4096
#define GPB  16            // WGs per batch group
#define RPW  64            // rows per WG (DM / GPB)
#define TPB  512
#define SP   132           // padded words per 128-col segment
#define HSW  1056          // 8 * SP, padded staged-state words

typedef unsigned long long u64;

// ---------------- Phase 1: bx = x @ B_w^T (fp32 NT GEMM) ----------------
__global__ __launch_bounds__(256) void bx_gemm_kernel(
    const float* __restrict__ X, const float* __restrict__ Bw,
    float* __restrict__ out)
{
    __shared__ float xs[16][68];
    __shared__ float bs[16][68];
    const int bm = blockIdx.x, bn = blockIdx.y;
    const int t  = threadIdx.x;
    const int tx = t & 15, ty = t >> 4;
    const int ml = t >> 2;
    const int kq = (t & 3) * 4;
    const float* xg = X  + (size_t)(bm * 64 + ml) * DM + kq;
    const float* bg = Bw + (size_t)(bn * 64 + ml) * DM + kq;
    float acc[4][4] = {};
    for (int k0 = 0; k0 < DM; k0 += 16) {
        float4 xv = *(const float4*)(xg + k0);
        float4 bv = *(const float4*)(bg + k0);
        __syncthreads();
        xs[kq+0][ml] = xv.x; xs[kq+1][ml] = xv.y; xs[kq+2][ml] = xv.z; xs[kq+3][ml] = xv.w;
        bs[kq+0][ml] = bv.x; bs[kq+1][ml] = bv.y; bs[kq+2][ml] = bv.z; bs[kq+3][ml] = bv.w;
        __syncthreads();
        #pragma unroll
        for (int kk = 0; kk < 16; ++kk) {
            float a[4], c[4];
            #pragma unroll
            for (int i = 0; i < 4; ++i) a[i] = xs[kk][ty*4+i];
            #pragma unroll
            for (int j = 0; j < 4; ++j) c[j] = bs[kk][tx*4+j];
            #pragma unroll
            for (int i = 0; i < 4; ++i)
                #pragma unroll
                for (int j = 0; j < 4; ++j)
                    acc[i][j] += a[i] * c[j];
        }
    }
    #pragma unroll
    for (int i = 0; i < 4; ++i) {
        float4 v = make_float4(acc[i][0], acc[i][1], acc[i][2], acc[i][3]);
        *(float4*)(out + (size_t)(bm*64 + ty*4 + i)*DM + bn*64 + tx*4) = v;
    }
}

// ---------------- Phase 2: fused scan, batch-split, tagged-atomic sync ----
// 64 WGs = 4 batch groups x 16. Each WG owns 64 rows; A slice in VGPRs
// (128/thread), C slice streamed from L2 in the deferred phase.
// Thread t: row = t>>3 (0..63), seg = t&7 (128 cols each).
// State exchanged as (tag<<32|float) u64 agent-scope relaxed atomics in
// hbuf[2][BSZ][DM]; slot parity = tag & 1. Zero-init => s_0 = 0, tag 0.
// Critical path: poll(2 words/thread) -> LDS stage -> A-matvec -> shfl
// -> tanh -> tagged store. C-matvec + y-store deferred (overlaps next poll).
__global__ __launch_bounds__(TPB, 2) void scan_kernel(
    const float* __restrict__ A, const float* __restrict__ Cw,
    const float* __restrict__ Dv, const float* __restrict__ X,
    float* __restrict__ Y, u64* hbuf)
{
    __shared__ float hs[HSW];            // staged s_k, seg-padded
    const int b   = blockIdx.x >> 4;     // batch
    const int gw  = blockIdx.x & 15;     // group-local WG
    const int r0  = gw * RPW;
    const int t   = threadIdx.x;
    const int row = t >> 3;              // 0..63 row within slice
    const int seg = t & 7;               // 128-col segment
    const bool lead = (seg == 0);

    // A row-slice -> registers (128 floats/thread)
    float ra[128];
    {
        const float* Ap = A + (size_t)(r0 + row) * DM + seg * 128;
        #pragma unroll
        for (int u = 0; u < 32; ++u) {
            float4 v = *(const float4*)(Ap + u*4);
            ra[u*4+0]=v.x; ra[u*4+1]=v.y; ra[u*4+2]=v.z; ra[u*4+3]=v.w;
        }
    }
    const float* Cp = Cw + (size_t)(r0 + row) * DM + seg * 128;
    const float dv  = Dv[r0 + row];

    for (int k = 0; k <= LSEQ; ++k) {
        // bx prefetch (independent, completes during poll)
        float bxv = 0.f;
        if (lead && k < LSEQ)
            bxv = Y[(size_t)b*LSEQ*DM + (size_t)k*DM + r0 + row];

        // ---- acquire s_k: poll 2 tagged u64s per thread ----
        u64* src = hbuf + (size_t)(k & 1) * BSZ * DM + (size_t)b * DM;
        u64 v0 = __hip_atomic_load(src + t,       __ATOMIC_RELAXED, __HIP_MEMORY_SCOPE_AGENT);
        u64 v1 = __hip_atomic_load(src + t + 512, __ATOMIC_RELAXED, __HIP_MEMORY_SCOPE_AGENT);
        const unsigned tag = (unsigned)k;
        int spins = 0;
        while ((((unsigned)(v0 >> 32)) != tag || ((unsigned)(v1 >> 32)) != tag)
               && ++spins < (1 << 20)) {
            if ((unsigned)(v0 >> 32) != tag)
                v0 = __hip_atomic_load(src + t,       __ATOMIC_RELAXED, __HIP_MEMORY_SCOPE_AGENT);
            if ((unsigned)(v1 >> 32) != tag)
                v1 = __hip_atomic_load(src + t + 512, __ATOMIC_RELAXED, __HIP_MEMORY_SCOPE_AGENT);
        }
        {
            int c0 = t, c1 = t + 512;
            hs[(c0 >> 7) * SP + (c0 & 127)] = __uint_as_float((unsigned)v0);
            hs[(c1 >> 7) * SP + (c1 & 127)] = __uint_as_float((unsigned)v1);
        }
        __syncthreads();

        // ---- critical path: A-matvec over this thread's 128-col segment ----
        float accA = 0.f;
        {
            const float4* h4p = (const float4*)(hs + seg * SP);
            #pragma unroll
            for (int u = 0; u < 32; ++u) {
                float4 h4 = h4p[u];
                accA += ra[u*4+0]*h4.x + ra[u*4+1]*h4.y + ra[u*4+2]*h4.z + ra[u*4+3]*h4.w;
            }
        }
        accA += __shfl_xor(accA, 1);
        accA += __shfl_xor(accA, 2);
        accA += __shfl_xor(accA, 4);
        if (lead && k < LSEQ) {
            float hv = tanhf(accA + bxv);
            u64 pk = ((u64)(unsigned)(k + 1) << 32) | (u64)__float_as_uint(hv);
            __hip_atomic_store(hbuf + (size_t)((k+1) & 1) * BSZ * DM + (size_t)b * DM + r0 + row,
                               pk, __ATOMIC_RELAXED, __HIP_MEMORY_SCOPE_AGENT);
        }

        // ---- deferred: C-matvec (C streamed from L2) + y-store ----
        if (k > 0) {
            float accC = 0.f;
            const float4* h4p = (const float4*)(hs + seg * SP);
            #pragma unroll
            for (int u = 0; u < 32; ++u) {
                float4 c4 = *(const float4*)(Cp + u*4);
                float4 h4 = h4p[u];
                accC += c4.x*h4.x + c4.y*h4.y + c4.z*h4.z + c4.w*h4.w;
            }
            accC += __shfl_xor(accC, 1);
            accC += __shfl_xor(accC, 2);
            accC += __shfl_xor(accC, 4);
            if (lead) {
                const size_t yoff = (size_t)b*LSEQ*DM + (size_t)(k-1)*DM + r0 + row;
                Y[yoff] = accC + dv * X[yoff];   // y_{k-1} = C s_k + D x_{k-1}
            }
        }
        __syncthreads();   // hs stable until all threads done reading it
    }
}

extern "C" void kernel_launch(void* const* d_in, const int* in_sizes, int n_in,
                              void* d_out, int out_size, void* d_ws, size_t ws_size,
                              hipStream_t stream)
{
    const float* X  = (const float*)d_in[0];
    const float* A  = (const float*)d_in[1];
    const float* Bw = (const float*)d_in[2];
    const float* Cw = (const float*)d_in[3];
    const float* Dv = (const float*)d_in[4];
    float* Y   = (float*)d_out;
    u64* hbuf  = (u64*)d_ws;

    // zero tagged state every launch: (0.0f, tag 0) == s_0 ready
    hipMemsetAsync(d_ws, 0, (size_t)2 * BSZ * DM * sizeof(u64), stream);

    dim3 g1((BSZ * LSEQ) / 64, DM / 64);
    bx_gemm_kernel<<<g1, 256, 0, stream>>>(X, Bw, Y);
    scan_kernel<<<BSZ * GPB, TPB, 0, stream>>>(A, Cw, Dv, X, Y, hbuf);
}

// Round 5
// 12194.418 us; speedup vs baseline: 3.0842x; 3.0842x over previous
//
#include <hip/hip_runtime.h>
#include <math.h>

#define DM   1024
#define BSZ  4
#define LSEQ 4096
#define GPB  32            // WGs per batch group
#define RPW  32            // rows per WG (DM / GPB)
#define TPB  256
#define SP   132           // padded words per 128-col segment
#define HSW  1056          // 8 * SP, padded staged-state words
#define RS   1056          // LDS row stride for C slice

typedef unsigned long long u64;

// ---------------- Phase 1: bx = x @ B_w^T (fp32 NT GEMM) ----------------
__global__ __launch_bounds__(256) void bx_gemm_kernel(
    const float* __restrict__ X, const float* __restrict__ Bw,
    float* __restrict__ out)
{
    __shared__ float xs[16][68];
    __shared__ float bs[16][68];
    const int bm = blockIdx.x, bn = blockIdx.y;
    const int t  = threadIdx.x;
    const int tx = t & 15, ty = t >> 4;
    const int ml = t >> 2;
    const int kq = (t & 3) * 4;
    const float* xg = X  + (size_t)(bm * 64 + ml) * DM + kq;
    const float* bg = Bw + (size_t)(bn * 64 + ml) * DM + kq;
    float acc[4][4] = {};
    for (int k0 = 0; k0 < DM; k0 += 16) {
        float4 xv = *(const float4*)(xg + k0);
        float4 bv = *(const float4*)(bg + k0);
        __syncthreads();
        xs[kq+0][ml] = xv.x; xs[kq+1][ml] = xv.y; xs[kq+2][ml] = xv.z; xs[kq+3][ml] = xv.w;
        bs[kq+0][ml] = bv.x; bs[kq+1][ml] = bv.y; bs[kq+2][ml] = bv.z; bs[kq+3][ml] = bv.w;
        __syncthreads();
        #pragma unroll
        for (int kk = 0; kk < 16; ++kk) {
            float a[4], c[4];
            #pragma unroll
            for (int i = 0; i < 4; ++i) a[i] = xs[kk][ty*4+i];
            #pragma unroll
            for (int j = 0; j < 4; ++j) c[j] = bs[kk][tx*4+j];
            #pragma unroll
            for (int i = 0; i < 4; ++i)
                #pragma unroll
                for (int j = 0; j < 4; ++j)
                    acc[i][j] += a[i] * c[j];
        }
    }
    #pragma unroll
    for (int i = 0; i < 4; ++i) {
        float4 v = make_float4(acc[i][0], acc[i][1], acc[i][2], acc[i][3]);
        *(float4*)(out + (size_t)(bm*64 + ty*4 + i)*DM + bn*64 + tx*4) = v;
    }
}

// ---------------- Phase 2: fused scan, batch-split, tagged-atomic sync ----
// 128 WGs = 4 batch groups x 32. WG owns 32 rows: A slice in VGPRs, C slice
// in LDS. Thread t: row = t>>3, seg = t&7 (128 cols). State exchanged as
// (tag<<32|float) u64 relaxed agent atomics in hbuf[2][BSZ][DM].
// Polling is HINT-BASED: only the 32 block-base words (col p*32, one per
// producer WG) are spin-polled (lane-merged -> ~8 reqs/wave/sweep). Values
// remain self-validating; after hints flip, bulk-load values once with a
// rare per-value retry. No fences anywhere.
// hs is double-buffered (parity k&1) -> ONE barrier per step: the stage
// barrier of step k+1 orders C-matvec(k) reads before stage(k+2) writes.
__global__ __launch_bounds__(TPB, 1) void scan_kernel(
    const float* __restrict__ A, const float* __restrict__ Cw,
    const float* __restrict__ Dv, const float* __restrict__ X,
    float* __restrict__ Y, u64* hbuf)
{
    extern __shared__ float lds[];          // [RPW*RS] C slice | 2*[HSW] staged h
    float* cs = lds;
    float* hs0 = lds + RPW * RS;
    const int b   = blockIdx.x >> 5;        // batch
    const int gw  = blockIdx.x & 31;        // group-local WG
    const int r0  = gw * RPW;
    const int t   = threadIdx.x;
    const int row = t >> 3;                 // 0..31 row within slice
    const int seg = t & 7;                  // 128-col segment
    const bool lead = (seg == 0);

    // A row-slice -> registers (128 floats/thread)
    float ra[128];
    {
        const float* Ap = A + (size_t)(r0 + row) * DM + seg * 128;
        #pragma unroll
        for (int u = 0; u < 32; ++u) {
            float4 v = *(const float4*)(Ap + u*4);
            ra[u*4+0]=v.x; ra[u*4+1]=v.y; ra[u*4+2]=v.z; ra[u*4+3]=v.w;
        }
    }
    // C row-slice -> LDS (coalesced), padded layout
    for (int i = 0; i < 32; ++i) {
        int idx = i * TPB + t;              // float4 index, 8192 total
        int rr  = idx >> 8;
        int c   = (idx & 255) * 4;
        float4 v = *(const float4*)(Cw + (size_t)(r0 + rr) * DM + c);
        *(float4*)(cs + rr * RS + (c >> 7) * SP + (c & 127)) = v;
    }
    const float dv = Dv[r0 + row];
    __syncthreads();

    const int c0 = t, c1 = t + 256, c2 = t + 512, c3 = t + 768;
    const int h0i = c0 & ~31, h1i = c1 & ~31, h2i = c2 & ~31, h3i = c3 & ~31;

    for (int k = 0; k <= LSEQ; ++k) {
        // bx prefetch (independent, completes during poll)
        float bxv = 0.f;
        if (lead && k < LSEQ)
            bxv = Y[(size_t)b*LSEQ*DM + (size_t)k*DM + r0 + row];

        u64* src = hbuf + (size_t)(k & 1) * BSZ * DM + (size_t)b * DM;
        const unsigned tag = (unsigned)k;

        // ---- Phase A: poll 4 hint words (block-base cols, lane-merged) ----
        u64 a0 = __hip_atomic_load(src + h0i, __ATOMIC_RELAXED, __HIP_MEMORY_SCOPE_AGENT);
        u64 a1 = __hip_atomic_load(src + h1i, __ATOMIC_RELAXED, __HIP_MEMORY_SCOPE_AGENT);
        u64 a2 = __hip_atomic_load(src + h2i, __ATOMIC_RELAXED, __HIP_MEMORY_SCOPE_AGENT);
        u64 a3 = __hip_atomic_load(src + h3i, __ATOMIC_RELAXED, __HIP_MEMORY_SCOPE_AGENT);
        int spins = 0;
        while ((((unsigned)(a0 >> 32)) != tag || ((unsigned)(a1 >> 32)) != tag ||
                ((unsigned)(a2 >> 32)) != tag || ((unsigned)(a3 >> 32)) != tag)
               && ++spins < (1 << 20)) {
            if ((unsigned)(a0 >> 32) != tag)
                a0 = __hip_atomic_load(src + h0i, __ATOMIC_RELAXED, __HIP_MEMORY_SCOPE_AGENT);
            if ((unsigned)(a1 >> 32) != tag)
                a1 = __hip_atomic_load(src + h1i, __ATOMIC_RELAXED, __HIP_MEMORY_SCOPE_AGENT);
            if ((unsigned)(a2 >> 32) != tag)
                a2 = __hip_atomic_load(src + h2i, __ATOMIC_RELAXED, __HIP_MEMORY_SCOPE_AGENT);
            if ((unsigned)(a3 >> 32) != tag)
                a3 = __hip_atomic_load(src + h3i, __ATOMIC_RELAXED, __HIP_MEMORY_SCOPE_AGENT);
        }
        // ---- Phase B: one-shot bulk value loads, rare per-value retry ----
        u64 v0 = __hip_atomic_load(src + c0, __ATOMIC_RELAXED, __HIP_MEMORY_SCOPE_AGENT);
        u64 v1 = __hip_atomic_load(src + c1, __ATOMIC_RELAXED, __HIP_MEMORY_SCOPE_AGENT);
        u64 v2 = __hip_atomic_load(src + c2, __ATOMIC_RELAXED, __HIP_MEMORY_SCOPE_AGENT);
        u64 v3 = __hip_atomic_load(src + c3, __ATOMIC_RELAXED, __HIP_MEMORY_SCOPE_AGENT);
        spins = 0;
        while ((((unsigned)(v0 >> 32)) != tag || ((unsigned)(v1 >> 32)) != tag ||
                ((unsigned)(v2 >> 32)) != tag || ((unsigned)(v3 >> 32)) != tag)
               && ++spins < (1 << 20)) {
            if ((unsigned)(v0 >> 32) != tag)
                v0 = __hip_atomic_load(src + c0, __ATOMIC_RELAXED, __HIP_MEMORY_SCOPE_AGENT);
            if ((unsigned)(v1 >> 32) != tag)
                v1 = __hip_atomic_load(src + c1, __ATOMIC_RELAXED, __HIP_MEMORY_SCOPE_AGENT);
            if ((unsigned)(v2 >> 32) != tag)
                v2 = __hip_atomic_load(src + c2, __ATOMIC_RELAXED, __HIP_MEMORY_SCOPE_AGENT);
            if ((unsigned)(v3 >> 32) != tag)
                v3 = __hip_atomic_load(src + c3, __ATOMIC_RELAXED, __HIP_MEMORY_SCOPE_AGENT);
        }
        float* hs = hs0 + (k & 1) * HSW;
        hs[(c0 >> 7) * SP + (c0 & 127)] = __uint_as_float((unsigned)v0);
        hs[(c1 >> 7) * SP + (c1 & 127)] = __uint_as_float((unsigned)v1);
        hs[(c2 >> 7) * SP + (c2 & 127)] = __uint_as_float((unsigned)v2);
        hs[(c3 >> 7) * SP + (c3 & 127)] = __uint_as_float((unsigned)v3);
        __syncthreads();   // the only barrier per step

        // ---- critical path: A-matvec over this thread's 128-col segment ----
        float accA = 0.f;
        {
            const float4* h4p = (const float4*)(hs + seg * SP);
            #pragma unroll
            for (int u = 0; u < 32; ++u) {
                float4 h4 = h4p[u];
                accA += ra[u*4+0]*h4.x + ra[u*4+1]*h4.y + ra[u*4+2]*h4.z + ra[u*4+3]*h4.w;
            }
        }
        accA += __shfl_xor(accA, 1);
        accA += __shfl_xor(accA, 2);
        accA += __shfl_xor(accA, 4);
        if (lead && k < LSEQ) {
            float hv = tanhf(accA + bxv);
            u64 pk = ((u64)(unsigned)(k + 1) << 32) | (u64)__float_as_uint(hv);
            __hip_atomic_store(hbuf + (size_t)((k+1) & 1) * BSZ * DM + (size_t)b * DM + r0 + row,
                               pk, __ATOMIC_RELAXED, __HIP_MEMORY_SCOPE_AGENT);
        }

        // ---- deferred: C-matvec (LDS) + y-store (overlaps next poll) ----
        if (k > 0) {
            float accC = 0.f;
            const float4* c4p = (const float4*)(cs + row * RS + seg * SP);
            const float4* h4p = (const float4*)(hs + seg * SP);
            #pragma unroll
            for (int u = 0; u < 32; ++u) {
                float4 c4 = c4p[u];
                float4 h4 = h4p[u];
                accC += c4.x*h4.x + c4.y*h4.y + c4.z*h4.z + c4.w*h4.w;
            }
            accC += __shfl_xor(accC, 1);
            accC += __shfl_xor(accC, 2);
            accC += __shfl_xor(accC, 4);
            if (lead) {
                const size_t yoff = (size_t)b*LSEQ*DM + (size_t)(k-1)*DM + r0 + row;
                Y[yoff] = accC + dv * X[yoff];   // y_{k-1} = C s_k + D x_{k-1}
            }
        }
        // no trailing barrier: hs double-buffer + next stage barrier cover it
    }
}

extern "C" void kernel_launch(void* const* d_in, const int* in_sizes, int n_in,
                              void* d_out, int out_size, void* d_ws, size_t ws_size,
                              hipStream_t stream)
{
    const float* X  = (const float*)d_in[0];
    const float* A  = (const float*)d_in[1];
    const float* Bw = (const float*)d_in[2];
    const float* Cw = (const float*)d_in[3];
    const float* Dv = (const float*)d_in[4];
    float* Y   = (float*)d_out;
    u64* hbuf  = (u64*)d_ws;

    // zero tagged state every launch: (0.0f, tag 0) == s_0 ready
    hipMemsetAsync(d_ws, 0, (size_t)2 * BSZ * DM * sizeof(u64), stream);

    dim3 g1((BSZ * LSEQ) / 64, DM / 64);
    bx_gemm_kernel<<<g1, 256, 0, stream>>>(X, Bw, Y);
    const size_t lds_bytes = (size_t)(RPW * RS + 2 * HSW) * sizeof(float);
    scan_kernel<<<BSZ * GPB, TPB, lds_bytes, stream>>>(A, Cw, Dv, X, Y, hbuf);
}

// Round 6
// 11065.694 us; speedup vs baseline: 3.3988x; 1.1020x over previous
//
#include <hip/hip_runtime.h>
#include <math.h>

#define DM   1024
#define BSZ  4
#define LSEQ 4096
#define GPB  32            // WGs per batch group
#define RPW  32            // rows per WG (DM / GPB)
#define TPB  512
#define SEGC 64            // columns per thread segment
#define SSP  68            // padded words per 64-col segment
#define HSW2 1088          // 16 * SSP : staged-state words per buffer
#define CRS  1092          // C row stride words (16*SSP + 4)

typedef unsigned long long u64;

// ---------------- Phase 1: bx = x @ B_w^T (fp32 NT GEMM) ----------------
__global__ __launch_bounds__(256) void bx_gemm_kernel(
    const float* __restrict__ X, const float* __restrict__ Bw,
    float* __restrict__ out)
{
    __shared__ float xs[16][68];
    __shared__ float bs[16][68];
    const int bm = blockIdx.x, bn = blockIdx.y;
    const int t  = threadIdx.x;
    const int tx = t & 15, ty = t >> 4;
    const int ml = t >> 2;
    const int kq = (t & 3) * 4;
    const float* xg = X  + (size_t)(bm * 64 + ml) * DM + kq;
    const float* bg = Bw + (size_t)(bn * 64 + ml) * DM + kq;
    float acc[4][4] = {};
    for (int k0 = 0; k0 < DM; k0 += 16) {
        float4 xv = *(const float4*)(xg + k0);
        float4 bv = *(const float4*)(bg + k0);
        __syncthreads();
        xs[kq+0][ml] = xv.x; xs[kq+1][ml] = xv.y; xs[kq+2][ml] = xv.z; xs[kq+3][ml] = xv.w;
        bs[kq+0][ml] = bv.x; bs[kq+1][ml] = bv.y; bs[kq+2][ml] = bv.z; bs[kq+3][ml] = bv.w;
        __syncthreads();
        #pragma unroll
        for (int kk = 0; kk < 16; ++kk) {
            float a[4], c[4];
            #pragma unroll
            for (int i = 0; i < 4; ++i) a[i] = xs[kk][ty*4+i];
            #pragma unroll
            for (int j = 0; j < 4; ++j) c[j] = bs[kk][tx*4+j];
            #pragma unroll
            for (int i = 0; i < 4; ++i)
                #pragma unroll
                for (int j = 0; j < 4; ++j)
                    acc[i][j] += a[i] * c[j];
        }
    }
    #pragma unroll
    for (int i = 0; i < 4; ++i) {
        float4 v = make_float4(acc[i][0], acc[i][1], acc[i][2], acc[i][3]);
        *(float4*)(out + (size_t)(bm*64 + ty*4 + i)*DM + bn*64 + tx*4) = v;
    }
}

// ---------------- Phase 2: fused scan, tagged-atomic sync, spec-poll ------
// 128 WGs = 4 batch groups x 32, 512 threads. Thread t: row = t>>4 (0..31),
// seg = t&15 (64 cols). A slice in VGPRs (64/thr), C slice in LDS (~140KB).
// State exchange: (tag<<32|float) u64 relaxed agent atomics, hbuf[2][BSZ][DM].
// Per step: finish-poll (spec loads issued LAST iteration) -> stage -> barrier
// -> A-matvec -> shfl(1,2,4,8) -> tanh -> tagged h-store -> issue spec loads
// for k+1 -> prefetch X/bx for k+1 -> C-matvec (LDS) + y-store.
// hs double-buffered => one barrier per step.
__global__ __launch_bounds__(TPB, 2) void scan_kernel(
    const float* __restrict__ A, const float* __restrict__ Cw,
    const float* __restrict__ Dv, const float* __restrict__ X,
    float* __restrict__ Y, u64* hbuf)
{
    extern __shared__ float lds[];          // [RPW*CRS] C | 2*[HSW2] staged h
    float* cs  = lds;
    float* hs0 = lds + RPW * CRS;
    const int b   = blockIdx.x >> 5;        // batch
    const int gw  = blockIdx.x & 31;        // group-local WG
    const int r0  = gw * RPW;
    const int t   = threadIdx.x;
    const int row = t >> 4;                 // 0..31
    const int seg = t & 15;                 // 64-col segment
    const bool lead = (seg == 0);

    // A row-slice -> registers (64 floats/thread)
    float ra[SEGC];
    {
        const float* Ap = A + (size_t)(r0 + row) * DM + seg * SEGC;
        #pragma unroll
        for (int u = 0; u < SEGC / 4; ++u) {
            float4 v = *(const float4*)(Ap + u*4);
            ra[u*4+0]=v.x; ra[u*4+1]=v.y; ra[u*4+2]=v.z; ra[u*4+3]=v.w;
        }
    }
    // C row-slice -> LDS (coalesced), seg-padded layout
    for (int i = 0; i < 16; ++i) {
        int idx = i * TPB + t;              // float4 index, 8192 total
        int rr  = idx >> 8;
        int c4  = idx & 255;
        float4 v = *(const float4*)(Cw + (size_t)(r0 + rr) * DM + c4 * 4);
        *(float4*)(cs + rr * CRS + (c4 >> 4) * SSP + (c4 & 15) * 4) = v;
    }
    const float dv = Dv[r0 + row];
    __syncthreads();

    const int c0 = t, c1 = t + 512;
    const int s0 = (c0 >> 6) * SSP + (c0 & 63);
    const int s1 = (c1 >> 6) * SSP + (c1 & 63);

    // spec loads for k=0 (tag 0 ready from memset) + bx_0 prefetch
    u64 v0 = __hip_atomic_load(hbuf + (size_t)b * DM + c0, __ATOMIC_RELAXED, __HIP_MEMORY_SCOPE_AGENT);
    u64 v1 = __hip_atomic_load(hbuf + (size_t)b * DM + c1, __ATOMIC_RELAXED, __HIP_MEMORY_SCOPE_AGENT);
    float bxv = 0.f;          // bx_k   (tanh at iteration k)
    float xv  = 0.f;          // x_{k-1} (y-store at iteration k)
    if (lead) bxv = Y[(size_t)b*LSEQ*DM + r0 + row];

    for (int k = 0; k <= LSEQ; ++k) {
        const unsigned tag = (unsigned)k;
        u64* src = hbuf + (size_t)(k & 1) * BSZ * DM + (size_t)b * DM;

        // ---- finish poll for s_k ----
        int spins = 0;
        while ((((unsigned)(v0 >> 32)) != tag || ((unsigned)(v1 >> 32)) != tag)
               && ++spins < (1 << 20)) {
            if ((unsigned)(v0 >> 32) != tag)
                v0 = __hip_atomic_load(src + c0, __ATOMIC_RELAXED, __HIP_MEMORY_SCOPE_AGENT);
            if ((unsigned)(v1 >> 32) != tag)
                v1 = __hip_atomic_load(src + c1, __ATOMIC_RELAXED, __HIP_MEMORY_SCOPE_AGENT);
        }
        float* hsk = hs0 + (k & 1) * HSW2;
        hsk[s0] = __uint_as_float((unsigned)v0);
        hsk[s1] = __uint_as_float((unsigned)v1);
        __syncthreads();   // the only barrier per step

        const float4* h4p = (const float4*)(hsk + seg * SSP);
        float xv_next = xv;
        if (k < LSEQ) {
            // ---- critical path: A-matvec over 64-col segment ----
            float accA = 0.f;
            #pragma unroll
            for (int u = 0; u < SEGC / 4; ++u) {
                float4 h4 = h4p[u];
                accA += ra[u*4+0]*h4.x + ra[u*4+1]*h4.y + ra[u*4+2]*h4.z + ra[u*4+3]*h4.w;
            }
            accA += __shfl_xor(accA, 1);
            accA += __shfl_xor(accA, 2);
            accA += __shfl_xor(accA, 4);
            accA += __shfl_xor(accA, 8);
            if (lead) {
                float hv = tanhf(accA + bxv);
                u64 pk = ((u64)(unsigned)(k + 1) << 32) | (u64)__float_as_uint(hv);
                __hip_atomic_store(hbuf + (size_t)((k+1) & 1) * BSZ * DM + (size_t)b * DM + r0 + row,
                                   pk, __ATOMIC_RELAXED, __HIP_MEMORY_SCOPE_AGENT);
            }
            // ---- issue speculative loads for step k+1 immediately ----
            u64* srcN = hbuf + (size_t)((k+1) & 1) * BSZ * DM + (size_t)b * DM;
            v0 = __hip_atomic_load(srcN + c0, __ATOMIC_RELAXED, __HIP_MEMORY_SCOPE_AGENT);
            v1 = __hip_atomic_load(srcN + c1, __ATOMIC_RELAXED, __HIP_MEMORY_SCOPE_AGENT);
            // prefetch next-step operands (after spec loads so the first
            // poll check's vmcnt wait doesn't cover these HBM loads)
            if (lead) {
                xv_next = X[(size_t)b*LSEQ*DM + (size_t)k*DM + r0 + row];   // x_k
                if (k + 1 < LSEQ)
                    bxv = Y[(size_t)b*LSEQ*DM + (size_t)(k+1)*DM + r0 + row];
            }
        }

        // ---- deferred: C-matvec (LDS) + y-store (overlaps poll wait) ----
        if (k > 0) {
            float accC = 0.f;
            const float4* c4p = (const float4*)(cs + row * CRS + seg * SSP);
            #pragma unroll
            for (int u = 0; u < SEGC / 4; ++u) {
                float4 c4 = c4p[u];
                float4 h4 = h4p[u];
                accC += c4.x*h4.x + c4.y*h4.y + c4.z*h4.z + c4.w*h4.w;
            }
            accC += __shfl_xor(accC, 1);
            accC += __shfl_xor(accC, 2);
            accC += __shfl_xor(accC, 4);
            accC += __shfl_xor(accC, 8);
            if (lead) {
                const size_t yoff = (size_t)b*LSEQ*DM + (size_t)(k-1)*DM + r0 + row;
                Y[yoff] = accC + dv * xv;        // y_{k-1} = C s_k + D x_{k-1}
            }
        }
        xv = xv_next;
    }
}

extern "C" void kernel_launch(void* const* d_in, const int* in_sizes, int n_in,
                              void* d_out, int out_size, void* d_ws, size_t ws_size,
                              hipStream_t stream)
{
    const float* X  = (const float*)d_in[0];
    const float* A  = (const float*)d_in[1];
    const float* Bw = (const float*)d_in[2];
    const float* Cw = (const float*)d_in[3];
    const float* Dv = (const float*)d_in[4];
    float* Y   = (float*)d_out;
    u64* hbuf  = (u64*)d_ws;

    // zero tagged state every launch: (0.0f, tag 0) == s_0 ready
    hipMemsetAsync(d_ws, 0, (size_t)2 * BSZ * DM * sizeof(u64), stream);

    dim3 g1((BSZ * LSEQ) / 64, DM / 64);
    bx_gemm_kernel<<<g1, 256, 0, stream>>>(X, Bw, Y);
    const size_t lds_bytes = (size_t)(RPW * CRS + 2 * HSW2) * sizeof(float);
    scan_kernel<<<BSZ * GPB, TPB, lds_bytes, stream>>>(A, Cw, Dv, X, Y, hbuf);
}

// Round 7
// 10700.771 us; speedup vs baseline: 3.5147x; 1.0341x over previous
//
#include <hip/hip_runtime.h>
#include <math.h>

#define DM   1024
#define BSZ  4
#define LSEQ 4096
#define GPB  32            // WGs per batch group (co-resident on one XCD)
#define RPW  32            // rows per WG (DM / GPB)
#define TPB  512
#define SEGC 64            // columns per thread segment
#define SSP  68            // padded words per 64-col segment
#define HSW2 1088          // 16 * SSP : staged-state words per buffer
#define CRS  1092          // C row stride words

typedef unsigned long long u64;

// ---------------- Phase 1: bx = x @ B_w^T (fp32 NT GEMM) ----------------
__global__ __launch_bounds__(256) void bx_gemm_kernel(
    const float* __restrict__ X, const float* __restrict__ Bw,
    float* __restrict__ out)
{
    __shared__ float xs[16][68];
    __shared__ float bs[16][68];
    const int bm = blockIdx.x, bn = blockIdx.y;
    const int t  = threadIdx.x;
    const int tx = t & 15, ty = t >> 4;
    const int ml = t >> 2;
    const int kq = (t & 3) * 4;
    const float* xg = X  + (size_t)(bm * 64 + ml) * DM + kq;
    const float* bg = Bw + (size_t)(bn * 64 + ml) * DM + kq;
    float acc[4][4] = {};
    for (int k0 = 0; k0 < DM; k0 += 16) {
        float4 xv = *(const float4*)(xg + k0);
        float4 bv = *(const float4*)(bg + k0);
        __syncthreads();
        xs[kq+0][ml] = xv.x; xs[kq+1][ml] = xv.y; xs[kq+2][ml] = xv.z; xs[kq+3][ml] = xv.w;
        bs[kq+0][ml] = bv.x; bs[kq+1][ml] = bv.y; bs[kq+2][ml] = bv.z; bs[kq+3][ml] = bv.w;
        __syncthreads();
        #pragma unroll
        for (int kk = 0; kk < 16; ++kk) {
            float a[4], c[4];
            #pragma unroll
            for (int i = 0; i < 4; ++i) a[i] = xs[kk][ty*4+i];
            #pragma unroll
            for (int j = 0; j < 4; ++j) c[j] = bs[kk][tx*4+j];
            #pragma unroll
            for (int i = 0; i < 4; ++i)
                #pragma unroll
                for (int j = 0; j < 4; ++j)
                    acc[i][j] += a[i] * c[j];
        }
    }
    #pragma unroll
    for (int i = 0; i < 4; ++i) {
        float4 v = make_float4(acc[i][0], acc[i][1], acc[i][2], acc[i][3]);
        *(float4*)(out + (size_t)(bm*64 + ty*4 + i)*DM + bn*64 + tx*4) = v;
    }
}

// Poll one tagged word: fast copy (XCD-L2, RMW-read) with bounded retries,
// then safe copy (agent/MALL). Latches fastok=0 if the fast copy provably
// never received the value the safe copy already has.
__device__ __forceinline__ u64 poll_word(u64* fast, u64* safe, unsigned tag,
                                         u64 v, int& fastok)
{
    if ((unsigned)(v >> 32) == tag) return v;
    if (fastok) {
        #pragma unroll 1
        for (int i = 0; i < 16; ++i) {
            v = __hip_atomic_fetch_add(fast, 0ULL, __ATOMIC_RELAXED,
                                       __HIP_MEMORY_SCOPE_WORKGROUP);
            if ((unsigned)(v >> 32) == tag) return v;
        }
    }
    int spins = 0;
    do {
        v = __hip_atomic_load(safe, __ATOMIC_RELAXED, __HIP_MEMORY_SCOPE_AGENT);
    } while ((unsigned)(v >> 32) != tag && ++spins < (1 << 20));
    if (fastok) {
        u64 f = __hip_atomic_fetch_add(fast, 0ULL, __ATOMIC_RELAXED,
                                       __HIP_MEMORY_SCOPE_WORKGROUP);
        if ((unsigned)(f >> 32) != tag) fastok = 0;   // fast path dead
    }
    return v;
}

// ---------------- Phase 2: fused scan, XCD-local tagged exchange ----------
// 256 WGs launched; residue r=blockIdx&7 picks role: r<4 -> batch group r
// (32 WGs, all with blockIdx%8==r -> same XCD under round-robin dispatch),
// r>=4 -> exit. State = (tag<<32|float) u64, DUAL copy:
//   fast: workgroup-scope store / fetch_add(0) read -> serviced at XCD L2
//   safe: agent-scope store/load -> MALL (correctness fallback, step 0, and
//         any consumer whose placement assumption failed)
// Per step: finish spec-poll -> stage LDS -> barrier -> A-matvec -> shfl
// -> tanh -> dual h-store -> issue spec polls k+1 -> bx/x prefetch ->
// deferred C-matvec (LDS) + y-store. hs double-buffered, 1 barrier/step.
__global__ __launch_bounds__(TPB, 1) void scan_kernel(
    const float* __restrict__ A, const float* __restrict__ Cw,
    const float* __restrict__ Dv, const float* __restrict__ X,
    float* __restrict__ Y, u64* hfast, u64* hsafe)
{
    const int r = blockIdx.x & 7;
    if (r >= BSZ) return;                    // 128 WGs exit immediately
    const int b  = r;                        // batch group
    const int gw = blockIdx.x >> 3;          // 0..31 within group
    const int r0 = gw * RPW;

    extern __shared__ float lds[];           // [RPW*CRS] C | 2*[HSW2] staged h
    float* cs  = lds;
    float* hs0 = lds + RPW * CRS;
    const int t   = threadIdx.x;
    const int row = t >> 4;                  // 0..31
    const int seg = t & 15;                  // 64-col segment
    const bool lead = (seg == 0);

    // A row-slice -> registers (64 floats/thread)
    float ra[SEGC];
    {
        const float* Ap = A + (size_t)(r0 + row) * DM + seg * SEGC;
        #pragma unroll
        for (int u = 0; u < SEGC / 4; ++u) {
            float4 v = *(const float4*)(Ap + u*4);
            ra[u*4+0]=v.x; ra[u*4+1]=v.y; ra[u*4+2]=v.z; ra[u*4+3]=v.w;
        }
    }
    // C row-slice -> LDS (coalesced), seg-padded layout
    for (int i = 0; i < 16; ++i) {
        int idx = i * TPB + t;
        int rr  = idx >> 8;
        int c4  = idx & 255;
        float4 v = *(const float4*)(Cw + (size_t)(r0 + rr) * DM + c4 * 4);
        *(float4*)(cs + rr * CRS + (c4 >> 4) * SSP + (c4 & 15) * 4) = v;
    }
    const float dv = Dv[r0 + row];
    __syncthreads();

    const int c0 = t, c1 = t + 512;
    const int s0 = (c0 >> 6) * SSP + (c0 & 63);
    const int s1 = (c1 >> 6) * SSP + (c1 & 63);
    int fastok = 1;

    // prologue spec for k=0: SAFE copy only (stale fast lines may survive
    // graph replays in L2; safe copy is freshly memset through MALL)
    u64 v0 = __hip_atomic_load(hsafe + (size_t)b * DM + c0, __ATOMIC_RELAXED, __HIP_MEMORY_SCOPE_AGENT);
    u64 v1 = __hip_atomic_load(hsafe + (size_t)b * DM + c1, __ATOMIC_RELAXED, __HIP_MEMORY_SCOPE_AGENT);
    float bxv = 0.f;          // bx_k   (tanh at iteration k)
    float xv  = 0.f;          // x_{k-1} (y-store at iteration k)
    if (lead) bxv = Y[(size_t)b*LSEQ*DM + r0 + row];

    for (int k = 0; k <= LSEQ; ++k) {
        const unsigned tag = (unsigned)k;
        const size_t slot = (size_t)(k & 1) * BSZ * DM + (size_t)b * DM;
        int dummy = 0;
        int& fo = (k == 0) ? dummy : fastok;

        v0 = poll_word(hfast + slot + c0, hsafe + slot + c0, tag, v0, fo);
        v1 = poll_word(hfast + slot + c1, hsafe + slot + c1, tag, v1, fo);

        float* hsk = hs0 + (k & 1) * HSW2;
        hsk[s0] = __uint_as_float((unsigned)v0);
        hsk[s1] = __uint_as_float((unsigned)v1);
        __syncthreads();   // the only barrier per step

        const float4* h4p = (const float4*)(hsk + seg * SSP);
        float xv_next = xv;
        if (k < LSEQ) {
            // ---- critical path: A-matvec over 64-col segment ----
            float accA = 0.f;
            #pragma unroll
            for (int u = 0; u < SEGC / 4; ++u) {
                float4 h4 = h4p[u];
                accA += ra[u*4+0]*h4.x + ra[u*4+1]*h4.y + ra[u*4+2]*h4.z + ra[u*4+3]*h4.w;
            }
            accA += __shfl_xor(accA, 1);
            accA += __shfl_xor(accA, 2);
            accA += __shfl_xor(accA, 4);
            accA += __shfl_xor(accA, 8);
            const size_t nslot = (size_t)((k+1) & 1) * BSZ * DM + (size_t)b * DM;
            if (lead) {
                float hv = tanhf(accA + bxv);
                u64 pk = ((u64)(unsigned)(k + 1) << 32) | (u64)__float_as_uint(hv);
                __hip_atomic_store(hfast + nslot + r0 + row, pk,
                                   __ATOMIC_RELAXED, __HIP_MEMORY_SCOPE_WORKGROUP);
                __hip_atomic_store(hsafe + nslot + r0 + row, pk,
                                   __ATOMIC_RELAXED, __HIP_MEMORY_SCOPE_AGENT);
            }
            // ---- issue speculative polls for step k+1 immediately ----
            if (fastok) {
                v0 = __hip_atomic_fetch_add(hfast + nslot + c0, 0ULL,
                                            __ATOMIC_RELAXED, __HIP_MEMORY_SCOPE_WORKGROUP);
                v1 = __hip_atomic_fetch_add(hfast + nslot + c1, 0ULL,
                                            __ATOMIC_RELAXED, __HIP_MEMORY_SCOPE_WORKGROUP);
            } else {
                v0 = __hip_atomic_load(hsafe + nslot + c0, __ATOMIC_RELAXED, __HIP_MEMORY_SCOPE_AGENT);
                v1 = __hip_atomic_load(hsafe + nslot + c1, __ATOMIC_RELAXED, __HIP_MEMORY_SCOPE_AGENT);
            }
            // prefetch next-step operands
            if (lead) {
                xv_next = X[(size_t)b*LSEQ*DM + (size_t)k*DM + r0 + row];   // x_k
                if (k + 1 < LSEQ)
                    bxv = Y[(size_t)b*LSEQ*DM + (size_t)(k+1)*DM + r0 + row];
            }
        }

        // ---- deferred: C-matvec (LDS) + y-store (overlaps spec polls) ----
        if (k > 0) {
            float accC = 0.f;
            const float4* c4p = (const float4*)(cs + row * CRS + seg * SSP);
            #pragma unroll
            for (int u = 0; u < SEGC / 4; ++u) {
                float4 c4 = c4p[u];
                float4 h4 = h4p[u];
                accC += c4.x*h4.x + c4.y*h4.y + c4.z*h4.z + c4.w*h4.w;
            }
            accC += __shfl_xor(accC, 1);
            accC += __shfl_xor(accC, 2);
            accC += __shfl_xor(accC, 4);
            accC += __shfl_xor(accC, 8);
            if (lead) {
                const size_t yoff = (size_t)b*LSEQ*DM + (size_t)(k-1)*DM + r0 + row;
                Y[yoff] = accC + dv * xv;        // y_{k-1} = C s_k + D x_{k-1}
            }
        }
        xv = xv_next;
    }
}

extern "C" void kernel_launch(void* const* d_in, const int* in_sizes, int n_in,
                              void* d_out, int out_size, void* d_ws, size_t ws_size,
                              hipStream_t stream)
{
    const float* X  = (const float*)d_in[0];
    const float* A  = (const float*)d_in[1];
    const float* Bw = (const float*)d_in[2];
    const float* Cw = (const float*)d_in[3];
    const float* Dv = (const float*)d_in[4];
    float* Y    = (float*)d_out;
    u64* hfast  = (u64*)d_ws;
    u64* hsafe  = hfast + (size_t)2 * BSZ * DM;

    // zero both tagged copies every launch: (0.0f, tag 0) == s_0 ready
    hipMemsetAsync(d_ws, 0, (size_t)4 * BSZ * DM * sizeof(u64), stream);

    dim3 g1((BSZ * LSEQ) / 64, DM / 64);
    bx_gemm_kernel<<<g1, 256, 0, stream>>>(X, Bw, Y);
    const size_t lds_bytes = (size_t)(RPW * CRS + 2 * HSW2) * sizeof(float);
    scan_kernel<<<256, TPB, lds_bytes, stream>>>(A, Cw, Dv, X, Y, hfast, hsafe);
}